// Round 11
// baseline (62.814 us; speedup 1.0000x reference)
//
#include <hip/hip_runtime.h>
#include <math.h>

#define NJ  16
#define BLK 256

// Affine 3x4: m[0..8] = row-major R, m[9..11] = p.
struct Mat { float m[12]; };

// C = A @ B (apply B then A): matches T_new = T_old @ A_j as mul(earlier, later).
__device__ __forceinline__ Mat mul(const Mat& A, const Mat& B) {
    Mat C;
    #pragma unroll
    for (int r = 0; r < 3; ++r) {
        float a0 = A.m[3*r+0], a1 = A.m[3*r+1], a2 = A.m[3*r+2];
        C.m[3*r+0] = a0*B.m[0] + a1*B.m[3] + a2*B.m[6];
        C.m[3*r+1] = a0*B.m[1] + a1*B.m[4] + a2*B.m[7];
        C.m[3*r+2] = a0*B.m[2] + a1*B.m[5] + a2*B.m[8];
        C.m[9+r]   = a0*B.m[9] + a1*B.m[10] + a2*B.m[11] + A.m[9+r];
    }
    return C;
}

// 16 lanes per batch element, one joint per lane. Scan over the 16-lane
// segment gives every lane its prefix pose: no redundant buildA, no replay.
__global__ __launch_bounds__(BLK) void poe_fwd(
    const float* __restrict__ q,        // B x 16
    const float* __restrict__ twist,    // 16 x 6 (uniform)
    const float* __restrict__ init_p,   // 3
    const float* __restrict__ init_rpy, // 3
    float* __restrict__ outT,           // B x 16
    float* __restrict__ outTw,          // B x 96
    int nb)
{
    const size_t gt   = (size_t)blockIdx.x * BLK + threadIdx.x; // global thread
    const int    lane = threadIdx.x & 63;
    const int    j    = lane & 15;           // my joint
    const size_t e    = gt >> 4;             // my batch element
    if (e >= (size_t)nb) return;

    // ---- q for my joint: one dword/lane, wave reads 256 B contiguous ----
    const float qj = q[e * NJ + j];

    // ---- my twist row (96 B table, L1 broadcast-ish) ----
    const float2* t2 = reinterpret_cast<const float2*>(twist) + 3 * j;
    float2 ta = t2[0], tb = t2[1], tc = t2[2];
    const float w0 = ta.x, w1 = ta.y, w2 = tb.x;
    const float v0 = tb.y, v1 = tc.x, v2 = tc.y;

    // ---- build my single A_j ----
    Mat P;
    {
        float theta = sqrtf(w0*w0 + w1*w1 + w2*w2) + 1e-12f;
        float inv   = __builtin_amdgcn_rcpf(theta);
        float wn0 = w0*inv, wn1 = w1*inv, wn2 = w2*inv;
        float vn0 = v0*inv, vn1 = v1*inv, vn2 = v2*inv;
        float qt  = qj * theta;
        float s   = __sinf(qt);
        float cth = __cosf(qt);
        float c   = 1.0f - cth;
        float ts  = qt - s;
        P.m[0] = cth + c*wn0*wn0;   P.m[1] = c*wn0*wn1 - s*wn2; P.m[2] = c*wn0*wn2 + s*wn1;
        P.m[3] = c*wn1*wn0 + s*wn2; P.m[4] = cth + c*wn1*wn1;   P.m[5] = c*wn1*wn2 - s*wn0;
        P.m[6] = c*wn2*wn0 - s*wn1; P.m[7] = c*wn2*wn1 + s*wn0; P.m[8] = cth + c*wn2*wn2;
        float cx0 = wn1*vn2 - wn2*vn1;
        float cx1 = wn2*vn0 - wn0*vn2;
        float cx2 = wn0*vn1 - wn1*vn0;
        float d   = wn0*vn0 + wn1*vn1 + wn2*vn2;
        float td  = ts * d;
        P.m[9]  = s*vn0 + c*cx0 + td*wn0;
        P.m[10] = s*vn1 + c*cx1 + td*wn1;
        P.m[11] = s*vn2 + c*cx2 + td*wn2;
    }

    // ---- segmented inclusive Kogge-Stone scan over 16-lane groups ----
    #pragma unroll
    for (int step = 1; step < 16; step <<= 1) {
        const bool use = (j >= step);
        const int  src = use ? lane - step : lane;
        Mat T;
        #pragma unroll
        for (int i = 0; i < 12; ++i) T.m[i] = __shfl(P.m[i], src, 64);
        Mat M = mul(T, P);
        #pragma unroll
        for (int i = 0; i < 12; ++i) P.m[i] = use ? M.m[i] : P.m[i];
    }
    // lane j holds A_0..A_j inclusive; lane 15 holds the full 16-joint chain.

    // ---- exclusive prefix = my entry pose ----
    Mat pose;
    {
        const int src = (j == 0) ? lane : lane - 1;
        #pragma unroll
        for (int i = 0; i < 12; ++i) pose.m[i] = __shfl(P.m[i], src, 64);
        const float id[12] = {1,0,0, 0,1,0, 0,0,1, 0,0,0};
        #pragma unroll
        for (int i = 0; i < 12; ++i) pose.m[i] = (j == 0) ? id[i] : pose.m[i];
    }

    // ---- tw_local for my joint; 24 B/lane, wave covers 1536 B contiguous ----
    {
        float p0 = pose.m[9], p1 = pose.m[10], p2 = pose.m[11];
        float u0 = v0 - (p1*w2 - p2*w1);
        float u1 = v1 - (p2*w0 - p0*w2);
        float u2 = v2 - (p0*w1 - p1*w0);
        float wl0 = pose.m[0]*w0 + pose.m[3]*w1 + pose.m[6]*w2;
        float wl1 = pose.m[1]*w0 + pose.m[4]*w1 + pose.m[7]*w2;
        float wl2 = pose.m[2]*w0 + pose.m[5]*w1 + pose.m[8]*w2;
        float vl0 = pose.m[0]*u0 + pose.m[3]*u1 + pose.m[6]*u2;
        float vl1 = pose.m[1]*u0 + pose.m[4]*u1 + pose.m[7]*u2;
        float vl2 = pose.m[2]*u0 + pose.m[5]*u1 + pose.m[8]*u2;
        float* twb = outTw + (e * NJ + j) * 6;
        *reinterpret_cast<float4*>(twb)     = make_float4(wl0, wl1, wl2, vl0);
        *reinterpret_cast<float2*>(twb + 4) = make_float2(vl1, vl2);
    }

    // ---- outT: lanes j<4 each produce one row of T_full @ T_init ----
    Mat F;
    {
        const int src = lane | 15;
        #pragma unroll
        for (int i = 0; i < 12; ++i) F.m[i] = __shfl(P.m[i], src, 64);
    }
    if (j < 4) {
        float rr = init_rpy[0], pt = init_rpy[1], yw = init_rpy[2];
        float sr = __sinf(rr), cr = __cosf(rr);
        float sp = __sinf(pt), cp = __cosf(pt);
        float sy = __sinf(yw), cy = __cosf(yw);
        float i00 = cy*cp, i01 = cy*sp*sr - sy*cr, i02 = cy*sp*cr + sy*sr;
        float i10 = sy*cp, i11 = sy*sp*sr + cy*cr, i12 = sy*sp*cr - cy*sr;
        float i20 = -sp,   i21 = cp*sr,            i22 = cp*cr;
        float ip0 = init_p[0], ip1 = init_p[1], ip2 = init_p[2];

        float r0 = (j == 0) ? F.m[0] : (j == 1) ? F.m[3] : F.m[6];
        float r1 = (j == 0) ? F.m[1] : (j == 1) ? F.m[4] : F.m[7];
        float r2 = (j == 0) ? F.m[2] : (j == 1) ? F.m[5] : F.m[8];
        float pr = (j == 0) ? F.m[9] : (j == 1) ? F.m[10] : F.m[11];
        float4 row;
        row.x = r0*i00 + r1*i10 + r2*i20;
        row.y = r0*i01 + r1*i11 + r2*i21;
        row.z = r0*i02 + r1*i12 + r2*i22;
        row.w = r0*ip0 + r1*ip1 + r2*ip2 + pr;
        if (j == 3) row = make_float4(0.f, 0.f, 0.f, 1.f);

        reinterpret_cast<float4*>(outT)[e * 4 + j] = row;
    }
}

extern "C" void kernel_launch(void* const* d_in, const int* in_sizes, int n_in,
                              void* d_out, int out_size, void* d_ws, size_t ws_size,
                              hipStream_t stream) {
    const float* q        = (const float*)d_in[0];
    const float* twist    = (const float*)d_in[1];
    const float* init_p   = (const float*)d_in[2];
    const float* init_rpy = (const float*)d_in[3];

    int nb = in_sizes[0] / NJ;   // B
    float* outT  = (float*)d_out;                  // B x 16 (4x4 matrices)
    float* outTw = outT + (size_t)nb * 16;         // B x 96 (Twistls)

    long long threads = (long long)nb * 16;        // 1 lane per joint
    int blocks = (int)((threads + BLK - 1) / BLK); // 16384 for B=262144
    poe_fwd<<<blocks, BLK, 0, stream>>>(q, twist, init_p, init_rpy, outT, outTw, nb);
}

// Round 12
// 44.507 us; speedup vs baseline: 1.4113x; 1.4113x over previous
//
#include <hip/hip_runtime.h>
#include <math.h>

#define NJ  16
#define BLK 256

// DPP quad_perm: cross-lane move WITHIN each 4-lane quad, executed on the
// VALU pipe (v_mov_b32_dpp) — zero DS ops, unlike __shfl (ds_bpermute).
// ctrl = p0 | p1<<2 | p2<<4 | p3<<6 : out-lane k reads in-lane p_k of quad.
template<int CTRL>
__device__ __forceinline__ float qperm(float x) {
    return __int_as_float(__builtin_amdgcn_update_dpp(
        __float_as_int(x), __float_as_int(x), CTRL, 0xF, 0xF, false));
}
#define QP_SHL1 144  // [0,0,1,2]: lane k <- k-1 (k>=1)
#define QP_SHL2 68   // [0,1,0,1]: lane k <- k-2 (k>=2)
#define QP_BCL3 255  // [3,3,3,3]: all lanes <- lane 3 of quad

// Affine 3x4: m[0..8] = row-major R, m[9..11] = p.
struct Mat { float m[12]; };

// C = A @ B (apply B then A): matches T_new = T_old @ A_j as mul(earlier, later).
__device__ __forceinline__ Mat mul(const Mat& A, const Mat& B) {
    Mat C;
    #pragma unroll
    for (int r = 0; r < 3; ++r) {
        float a0 = A.m[3*r+0], a1 = A.m[3*r+1], a2 = A.m[3*r+2];
        C.m[3*r+0] = a0*B.m[0] + a1*B.m[3] + a2*B.m[6];
        C.m[3*r+1] = a0*B.m[1] + a1*B.m[4] + a2*B.m[7];
        C.m[3*r+2] = a0*B.m[2] + a1*B.m[5] + a2*B.m[8];
        C.m[9+r]   = a0*B.m[9] + a1*B.m[10] + a2*B.m[11] + A.m[9+r];
    }
    return C;
}

// srodrigues for one joint: tw6 = (w0..w2, v0..v2), angle qj.
__device__ __forceinline__ Mat buildA(const float* tw6, float qj) {
    float w0 = tw6[0], w1 = tw6[1], w2 = tw6[2];
    float v0 = tw6[3], v1 = tw6[4], v2 = tw6[5];
    float theta = sqrtf(w0*w0 + w1*w1 + w2*w2) + 1e-12f;
    float inv   = __builtin_amdgcn_rcpf(theta);
    float wn0 = w0*inv, wn1 = w1*inv, wn2 = w2*inv;
    float vn0 = v0*inv, vn1 = v1*inv, vn2 = v2*inv;
    float qt  = qj * theta;
    float s   = __sinf(qt);
    float cth = __cosf(qt);
    float c   = 1.0f - cth;
    float ts  = qt - s;
    Mat A;
    A.m[0] = cth + c*wn0*wn0;   A.m[1] = c*wn0*wn1 - s*wn2; A.m[2] = c*wn0*wn2 + s*wn1;
    A.m[3] = c*wn1*wn0 + s*wn2; A.m[4] = cth + c*wn1*wn1;   A.m[5] = c*wn1*wn2 - s*wn0;
    A.m[6] = c*wn2*wn0 - s*wn1; A.m[7] = c*wn2*wn1 + s*wn0; A.m[8] = cth + c*wn2*wn2;
    float cx0 = wn1*vn2 - wn2*vn1;
    float cx1 = wn2*vn0 - wn0*vn2;
    float cx2 = wn0*vn1 - wn1*vn0;
    float d   = wn0*vn0 + wn1*vn1 + wn2*vn2;
    float td  = ts * d;
    A.m[9]  = s*vn0 + c*cx0 + td*wn0;
    A.m[10] = s*vn1 + c*cx1 + td*wn1;
    A.m[11] = s*vn2 + c*cx2 + td*wn2;
    return A;
}

// 4 lanes per batch element; lane handles 4 consecutive joints; quad scan
// done entirely with DPP quad_perm (VALU pipe) — zero DS traffic.
__global__ __launch_bounds__(BLK) void poe_fwd(
    const float* __restrict__ q,        // B x 16
    const float* __restrict__ twist,    // 16 x 6 (uniform)
    const float* __restrict__ init_p,   // 3
    const float* __restrict__ init_rpy, // 3
    float* __restrict__ outT,           // B x 16
    float* __restrict__ outTw,          // B x 96
    int nb)
{
    const int g = blockIdx.x * BLK + threadIdx.x;   // global lane
    const int e = g >> 2;                           // batch element
    const int s = g & 3;                            // segment (joints 4s..4s+3)
    if (e >= nb) return;

    float qk[4];
    {
        float4 t = reinterpret_cast<const float4*>(q)[(size_t)e * 4 + s];
        qk[0] = t.x; qk[1] = t.y; qk[2] = t.z; qk[3] = t.w;
    }

    // twist rows 4s..4s+3 (24 floats, L1-resident).
    float tws[24];
    {
        const float4* t4 = reinterpret_cast<const float4*>(twist) + s * 6;
        #pragma unroll
        for (int i = 0; i < 6; ++i) {
            float4 t = t4[i];
            tws[4*i+0] = t.x; tws[4*i+1] = t.y; tws[4*i+2] = t.z; tws[4*i+3] = t.w;
        }
    }

    // ---- phase 1: serial product of my segment ----
    Mat P = buildA(&tws[0], qk[0]);
    #pragma unroll
    for (int k = 1; k < 4; ++k)
        P = mul(P, buildA(&tws[6*k], qk[k]));

    // ---- inclusive scan over the quad via DPP (steps 1, 2) ----
    {
        Mat T;
        #pragma unroll
        for (int i = 0; i < 12; ++i) T.m[i] = qperm<QP_SHL1>(P.m[i]);
        Mat M = mul(T, P);
        #pragma unroll
        for (int i = 0; i < 12; ++i) P.m[i] = (s >= 1) ? M.m[i] : P.m[i];
    }
    {
        Mat T;
        #pragma unroll
        for (int i = 0; i < 12; ++i) T.m[i] = qperm<QP_SHL2>(P.m[i]);
        Mat M = mul(T, P);
        #pragma unroll
        for (int i = 0; i < 12; ++i) P.m[i] = (s >= 2) ? M.m[i] : P.m[i];
    }

    // ---- exclusive prefix = entry pose for my segment ----
    Mat pose;
    {
        #pragma unroll
        for (int i = 0; i < 12; ++i) pose.m[i] = qperm<QP_SHL1>(P.m[i]);
        const float id[12] = {1,0,0, 0,1,0, 0,0,1, 0,0,0};
        #pragma unroll
        for (int i = 0; i < 12; ++i) pose.m[i] = (s == 0) ? id[i] : pose.m[i];
    }

    // ---- phase 2: tw_local for my 4 joints; immediate float2 stores ----
    float2* twb = reinterpret_cast<float2*>(outTw) + (size_t)g * 12;
    #pragma unroll
    for (int k = 0; k < 4; ++k) {
        const float* t6 = &tws[6*k];
        float w0 = t6[0], w1 = t6[1], w2 = t6[2];
        float v0 = t6[3], v1 = t6[4], v2 = t6[5];
        float p0 = pose.m[9], p1 = pose.m[10], p2 = pose.m[11];
        float u0 = v0 - (p1*w2 - p2*w1);
        float u1 = v1 - (p2*w0 - p0*w2);
        float u2 = v2 - (p0*w1 - p1*w0);
        float wl0 = pose.m[0]*w0 + pose.m[3]*w1 + pose.m[6]*w2;
        float wl1 = pose.m[1]*w0 + pose.m[4]*w1 + pose.m[7]*w2;
        float wl2 = pose.m[2]*w0 + pose.m[5]*w1 + pose.m[8]*w2;
        float vl0 = pose.m[0]*u0 + pose.m[3]*u1 + pose.m[6]*u2;
        float vl1 = pose.m[1]*u0 + pose.m[4]*u1 + pose.m[7]*u2;
        float vl2 = pose.m[2]*u0 + pose.m[5]*u1 + pose.m[8]*u2;
        twb[3*k+0] = make_float2(wl0, wl1);
        twb[3*k+1] = make_float2(wl2, vl0);
        twb[3*k+2] = make_float2(vl1, vl2);
        if (k < 3)
            pose = mul(pose, buildA(t6, qk[k]));
    }

    // ---- final: full-chain product from quad lane 3 (DPP broadcast) ----
    Mat F;
    #pragma unroll
    for (int i = 0; i < 12; ++i) F.m[i] = qperm<QP_BCL3>(P.m[i]);

    float rr = init_rpy[0], pt = init_rpy[1], yw = init_rpy[2];
    float sr = __sinf(rr), cr = __cosf(rr);
    float sp = __sinf(pt), cp = __cosf(pt);
    float sy = __sinf(yw), cy = __cosf(yw);
    float i00 = cy*cp, i01 = cy*sp*sr - sy*cr, i02 = cy*sp*cr + sy*sr;
    float i10 = sy*cp, i11 = sy*sp*sr + cy*cr, i12 = sy*sp*cr - cy*sr;
    float i20 = -sp,   i21 = cp*sr,            i22 = cp*cr;
    float ip0 = init_p[0], ip1 = init_p[1], ip2 = init_p[2];

    float r0 = (s == 0) ? F.m[0] : (s == 1) ? F.m[3] : F.m[6];
    float r1 = (s == 0) ? F.m[1] : (s == 1) ? F.m[4] : F.m[7];
    float r2 = (s == 0) ? F.m[2] : (s == 1) ? F.m[5] : F.m[8];
    float pr = (s == 0) ? F.m[9] : (s == 1) ? F.m[10] : F.m[11];
    float4 row;
    row.x = r0*i00 + r1*i10 + r2*i20;
    row.y = r0*i01 + r1*i11 + r2*i21;
    row.z = r0*i02 + r1*i12 + r2*i22;
    row.w = r0*ip0 + r1*ip1 + r2*ip2 + pr;
    if (s == 3) row = make_float4(0.f, 0.f, 0.f, 1.f);

    reinterpret_cast<float4*>(outT)[(size_t)g] = row;
}

extern "C" void kernel_launch(void* const* d_in, const int* in_sizes, int n_in,
                              void* d_out, int out_size, void* d_ws, size_t ws_size,
                              hipStream_t stream) {
    const float* q        = (const float*)d_in[0];
    const float* twist    = (const float*)d_in[1];
    const float* init_p   = (const float*)d_in[2];
    const float* init_rpy = (const float*)d_in[3];

    int nb = in_sizes[0] / NJ;   // B
    float* outT  = (float*)d_out;                  // B x 16 (4x4 matrices)
    float* outTw = outT + (size_t)nb * 16;         // B x 96 (Twistls)

    int threads = nb * 4;                          // 4 lanes per element
    int blocks  = (threads + BLK - 1) / BLK;
    poe_fwd<<<blocks, BLK, 0, stream>>>(q, twist, init_p, init_rpy, outT, outTw, nb);
}